// Round 6
// baseline (941.972 us; speedup 1.0000x reference)
//
#include <hip/hip_runtime.h>
#include <stdint.h>

typedef unsigned short u16;

#define B_   2
#define S_   2048
#define H_   4096
#define NH   32
#define NKV  8
#define HD   128
#define KVD  (NKV * HD)   // 1024
#define BS   (B_ * S_)    // 4096
#define QS   6144         // QKV row stride (Q 0..4095 | K 4096..5119 | V 5120..6143)
#define KOFF 4096
#define VOFF 5120

typedef __bf16 bf16x8 __attribute__((ext_vector_type(8)));
typedef u16    u16x8  __attribute__((ext_vector_type(8)));
typedef u16    u16x4  __attribute__((ext_vector_type(4)));
typedef float  f32x4  __attribute__((ext_vector_type(4)));

__device__ __forceinline__ bf16x8 as_bf16x8(u16x8 v) { return __builtin_bit_cast(bf16x8, v); }

__device__ __forceinline__ float bf2f(u16 u) {
  union { uint32_t u; float f; } v; v.u = ((uint32_t)u) << 16; return v.f;
}
// single v_cvt instruction, RNE — numerically identical to manual round-half-even
__device__ __forceinline__ u16 f2bf(float f) {
  return __builtin_bit_cast(u16, (__bf16)f);
}

// async global->LDS, 16B per lane; LDS dest must be wave-uniform-base + lane*16
__device__ __forceinline__ void gload_lds16(const void* g, void* l) {
  __builtin_amdgcn_global_load_lds((const __attribute__((address_space(1))) void*)g,
                                   (__attribute__((address_space(3))) void*)l, 16, 0, 0);
}

// ---------------------------------------------------------------------------
// fp32 -> bf16 elementwise (vectorized, 8 elems/thread)
// ---------------------------------------------------------------------------
__global__ __launch_bounds__(256) void conv_bf16(const float* __restrict__ in,
                                                 u16* __restrict__ out) {
  size_t i = ((size_t)blockIdx.x * 256 + threadIdx.x) * 8;
  float4 a = *(const float4*)(in + i);
  float4 b = *(const float4*)(in + i + 4);
  u16x8 h;
  h[0] = f2bf(a.x); h[1] = f2bf(a.y); h[2] = f2bf(a.z); h[3] = f2bf(a.w);
  h[4] = f2bf(b.x); h[5] = f2bf(b.y); h[6] = f2bf(b.z); h[7] = f2bf(b.w);
  *(u16x8*)(out + i) = h;
}

// ---------------------------------------------------------------------------
// Convert + transpose: fp32 in[R][C] -> bf16 out[C][R]; 64x64 tiles.
// ---------------------------------------------------------------------------
__global__ __launch_bounds__(256) void conv_transpose_w(const float* __restrict__ in,
                                                        u16* __restrict__ out,
                                                        int ldi, int ldo) {
  __shared__ u16 tile[64][72];
  int r0 = blockIdx.x * 64, c0 = blockIdx.y * 64;
  int t = threadIdx.x;
  {
    int row = t >> 4, col = (t & 15) * 4;
#pragma unroll
    for (int rep = 0; rep < 4; ++rep) {
      int r = row + rep * 16;
      float4 v = *(const float4*)(in + (size_t)(r0 + r) * ldi + c0 + col);
      u16x4 h;
      h[0] = f2bf(v.x); h[1] = f2bf(v.y); h[2] = f2bf(v.z); h[3] = f2bf(v.w);
      *(u16x4*)&tile[r][col] = h;
    }
  }
  __syncthreads();
  {
    int row = t >> 2, c8 = (t & 3) * 8;
#pragma unroll
    for (int it = 0; it < 2; ++it) {
      int rr = c8 + it * 32;
      u16x8 v;
#pragma unroll
      for (int j = 0; j < 8; ++j) v[j] = tile[rr + j][row];
      *(u16x8*)(out + (size_t)(c0 + row) * ldo + r0 + rr) = v;
    }
  }
}

// ---------------------------------------------------------------------------
// Merged Wq/Wk/Wv convert+transpose (one dispatch): z=0 Wq, z=1 Wk, z=2 Wv.
// z>0 matrices have only 16 col-tiles; excess blocks exit.
// ---------------------------------------------------------------------------
__global__ __launch_bounds__(256) void conv_transpose_w3(const float* __restrict__ Wq,
                                                         const float* __restrict__ Wk,
                                                         const float* __restrict__ Wv,
                                                         u16* __restrict__ Wtq,
                                                         u16* __restrict__ Wtk,
                                                         u16* __restrict__ Wtv) {
  __shared__ u16 tile[64][72];
  int z = blockIdx.z;
  if (z > 0 && blockIdx.y >= 16) return;
  const float* in = (z == 0) ? Wq : (z == 1) ? Wk : Wv;
  u16* out        = (z == 0) ? Wtq : (z == 1) ? Wtk : Wtv;
  int ldi = (z == 0) ? H_ : KVD;
  int r0 = blockIdx.x * 64, c0 = blockIdx.y * 64;
  int t = threadIdx.x;
  {
    int row = t >> 4, col = (t & 15) * 4;
#pragma unroll
    for (int rep = 0; rep < 4; ++rep) {
      int r = row + rep * 16;
      float4 v = *(const float4*)(in + (size_t)(r0 + r) * ldi + c0 + col);
      u16x4 h;
      h[0] = f2bf(v.x); h[1] = f2bf(v.y); h[2] = f2bf(v.z); h[3] = f2bf(v.w);
      *(u16x4*)&tile[r][col] = h;
    }
  }
  __syncthreads();
  {
    int row = t >> 2, c8 = (t & 3) * 8;
#pragma unroll
    for (int it = 0; it < 2; ++it) {
      int rr = c8 + it * 32;
      u16x8 v;
#pragma unroll
      for (int j = 0; j < 8; ++j) v[j] = tile[rr + j][row];
      *(u16x8*)(out + (size_t)(c0 + row) * H_ + r0 + rr) = v;
    }
  }
}

// ---------------------------------------------------------------------------
// V transpose (bf16): QKV[b*S_+s][VOFF+kvh*HD+d] -> Vt[((b*NKV+kvh)*HD+d)*S_+s]
// ---------------------------------------------------------------------------
__global__ __launch_bounds__(256) void transpose_v(const u16* __restrict__ QKV,
                                                   u16* __restrict__ Vt) {
  __shared__ u16 tile[64][72];
  int g = blockIdx.z;
  const u16* in = QKV + (size_t)(g >> 3) * ((size_t)S_ * QS) + VOFF + (size_t)(g & 7) * HD;
  u16* out = Vt + (size_t)g * ((size_t)HD * S_);
  int r0 = blockIdx.x * 64, c0 = blockIdx.y * 64;
  int t = threadIdx.x;
  int row = t >> 2, c8 = (t & 3) * 8;
#pragma unroll
  for (int it = 0; it < 2; ++it) {
    int col = c8 + it * 32;
    *(u16x8*)&tile[row][col] = *(const u16x8*)(in + (size_t)(r0 + row) * QS + c0 + col);
  }
  __syncthreads();
#pragma unroll
  for (int it = 0; it < 2; ++it) {
    int rr = c8 + it * 32;
    u16x8 v;
#pragma unroll
    for (int j = 0; j < 8; ++j) v[j] = tile[rr + j][row];
    *(u16x8*)(out + (size_t)(c0 + row) * S_ + r0 + rr) = v;
  }
}

// ---------------------------------------------------------------------------
// C[M][N] = A[M][K] @ Bt[N][K]^T.  A bf16, C bf16 or fp32.
// m97 structure: 128x128 tile, BK=32, global_load_lds dwordx4 staging,
// 4 waves of 64x64, 16x16x32 bf16 MFMA.
// ---------------------------------------------------------------------------
template <bool C_F32>
__global__ __launch_bounds__(256) void gemm_bt_lds(const u16* __restrict__ A,
                                                   const u16* __restrict__ Bt,
                                                   void* __restrict__ Cp,
                                                   int M, int N, int K) {
  __shared__ __align__(16) u16 lsA[128][32];
  __shared__ __align__(16) u16 lsB[128][32];
  int t = threadIdx.x;
  int lane = t & 63;
  int w = t >> 6;
  int wm = (w >> 1) * 64, wn = (w & 1) * 64;
  int bm = blockIdx.x * 128, bn = blockIdx.y * 128;
  int fr = lane & 15, kq = lane >> 4;
  f32x4 acc[4][4] = {};

  int sr = t >> 2, sc = (t & 3) * 8;
  const u16* Ar0 = A + (size_t)(bm + sr) * K + sc;
  const u16* Ar1 = A + (size_t)(bm + sr + 64) * K + sc;
  const u16* Br0 = Bt + (size_t)(bn + sr) * K + sc;
  const u16* Br1 = Bt + (size_t)(bn + sr + 64) * K + sc;
  u16* lA0 = &lsA[sr][sc];
  u16* lA1 = &lsA[sr + 64][sc];
  u16* lB0 = &lsB[sr][sc];
  u16* lB1 = &lsB[sr + 64][sc];

  for (int k0 = 0; k0 < K; k0 += 32) {
    gload_lds16(Ar0 + k0, lA0);
    gload_lds16(Ar1 + k0, lA1);
    gload_lds16(Br0 + k0, lB0);
    gload_lds16(Br1 + k0, lB1);
    __syncthreads();  // drains vmcnt(0): LDS tiles complete
    bf16x8 af[4], bfr[4];
#pragma unroll
    for (int i = 0; i < 4; ++i) af[i] = as_bf16x8(*(const u16x8*)&lsA[wm + i * 16 + fr][kq * 8]);
#pragma unroll
    for (int j = 0; j < 4; ++j) bfr[j] = as_bf16x8(*(const u16x8*)&lsB[wn + j * 16 + fr][kq * 8]);
#pragma unroll
    for (int i = 0; i < 4; ++i)
#pragma unroll
      for (int j = 0; j < 4; ++j)
        acc[i][j] = __builtin_amdgcn_mfma_f32_16x16x32_bf16(af[i], bfr[j], acc[i][j], 0, 0, 0);
    __syncthreads();  // protect LDS from next-iter staging
  }
#pragma unroll
  for (int i = 0; i < 4; ++i)
#pragma unroll
    for (int j = 0; j < 4; ++j)
#pragma unroll
      for (int r = 0; r < 4; ++r) {
        int row = bm + wm + i * 16 + kq * 4 + r;
        int col = bn + wn + j * 16 + fr;
        if (C_F32) ((float*)Cp)[(size_t)row * N + col] = acc[i][j][r];
        else       ((u16*)Cp)[(size_t)row * N + col] = f2bf(acc[i][j][r]);
      }
}

// ---------------------------------------------------------------------------
// Fused QKV projection: C[4096][6144] = Xb @ [Wq | Wk | Wv].
// Same m97 body as gemm_bt_lds; B-matrix selected per block (uniform branch).
// 32x48 = 1536 blocks = 6/CU.
// ---------------------------------------------------------------------------
__global__ __launch_bounds__(256) void gemm_qkv(const u16* __restrict__ A,
                                                const u16* __restrict__ Wtq,
                                                const u16* __restrict__ Wtk,
                                                const u16* __restrict__ Wtv,
                                                u16* __restrict__ C) {
  const int K = H_;
  __shared__ __align__(16) u16 lsA[128][32];
  __shared__ __align__(16) u16 lsB[128][32];
  int t = threadIdx.x;
  int lane = t & 63;
  int w = t >> 6;
  int wm = (w >> 1) * 64, wn = (w & 1) * 64;
  int bm = blockIdx.x * 128;
  int by = blockIdx.y;                 // 0..47
  const u16* Bt; int bnl;
  if (by < 32)      { Bt = Wtq; bnl = by * 128; }
  else if (by < 40) { Bt = Wtk; bnl = (by - 32) * 128; }
  else              { Bt = Wtv; bnl = (by - 40) * 128; }
  int bn = by * 128;                   // global col in QKV space
  int fr = lane & 15, kq = lane >> 4;
  f32x4 acc[4][4] = {};

  int sr = t >> 2, sc = (t & 3) * 8;
  const u16* Ar0 = A + (size_t)(bm + sr) * K + sc;
  const u16* Ar1 = Ar0 + (size_t)64 * K;
  const u16* Br0 = Bt + (size_t)(bnl + sr) * K + sc;
  const u16* Br1 = Br0 + (size_t)64 * K;
  u16* lA0 = &lsA[sr][sc];
  u16* lA1 = &lsA[sr + 64][sc];
  u16* lB0 = &lsB[sr][sc];
  u16* lB1 = &lsB[sr + 64][sc];

  for (int k0 = 0; k0 < K; k0 += 32) {
    gload_lds16(Ar0 + k0, lA0);
    gload_lds16(Ar1 + k0, lA1);
    gload_lds16(Br0 + k0, lB0);
    gload_lds16(Br1 + k0, lB1);
    __syncthreads();
    bf16x8 af[4], bfr[4];
#pragma unroll
    for (int i = 0; i < 4; ++i) af[i] = as_bf16x8(*(const u16x8*)&lsA[wm + i * 16 + fr][kq * 8]);
#pragma unroll
    for (int j = 0; j < 4; ++j) bfr[j] = as_bf16x8(*(const u16x8*)&lsB[wn + j * 16 + fr][kq * 8]);
#pragma unroll
    for (int i = 0; i < 4; ++i)
#pragma unroll
      for (int j = 0; j < 4; ++j)
        acc[i][j] = __builtin_amdgcn_mfma_f32_16x16x32_bf16(af[i], bfr[j], acc[i][j], 0, 0, 0);
    __syncthreads();
  }
#pragma unroll
  for (int i = 0; i < 4; ++i)
#pragma unroll
    for (int j = 0; j < 4; ++j)
#pragma unroll
      for (int r = 0; r < 4; ++r) {
        int row = bm + wm + i * 16 + kq * 4 + r;
        int col = bn + wn + j * 16 + fr;
        C[(size_t)row * QS + col] = f2bf(acc[i][j][r]);
      }
}

// ---------------------------------------------------------------------------
// RoPE in-place on QKV (Q heads hh=0..31 at col hh*128; K heads hh=32..39
// at col KOFF+(hh-32)*128 == hh*128 — unified addressing).
// ---------------------------------------------------------------------------
__global__ __launch_bounds__(256) void rope_kernel(u16* __restrict__ QKV) {
  int idx = blockIdx.x * 256 + threadIdx.x;  // BS * 40 * 64 total
  int j = idx & 63;
  int rem = idx >> 6;
  int hh = rem % 40;
  int tok = rem / 40;
  float p = (float)(tok % S_);
  float freq = __expf((float)j * (-9.210340371976184f / 64.0f));  // 10000^(-j/64)
  float sn, cs;
  __sincosf(p * freq, &sn, &cs);
  u16* base = QKV + (size_t)tok * QS + (size_t)hh * HD;
  float x1 = bf2f(base[j]), x2 = bf2f(base[j + 64]);
  base[j]      = f2bf(x1 * cs - x2 * sn);
  base[j + 64] = f2bf(x2 * cs + x1 * sn);
}

// ---------------------------------------------------------------------------
// Flash attention, causal, GQA(4).
// This round: V LDS tile re-laid as 64 rows x 256B (two d-rows per LDS row)
// with K-style 16B-chunk XOR swizzle (chunk' = c ^ (row&15)).  Both write
// and PV b128 read hit the minimal 8-lanes-per-bank-quad aliasing — fixes
// round-4's 9.7M bank conflicts with zero repack VALU.
// grid: (S_/32, NKV, B_), 8 waves/block; wave w: head kvh*4+(w&3),
// q-subtile u=(w>>2).  K/V staged in LDS once per iter, shared by 8 waves.
// T14 async-STAGE: tile kt+1 loaded to regs after staging barrier.
// qt reversed so longest (diagonal-heavy) blocks dispatch first.
// ---------------------------------------------------------------------------
__global__ __launch_bounds__(512) void flash_attn(const u16* __restrict__ QKV,
                                                  const u16* __restrict__ Vt,
                                                  u16* __restrict__ O) {
  __shared__ __align__(16) u16 Ks[64 * 128];   // [kv 64][d 128], XOR-swizzled
  __shared__ __align__(16) u16 Vs[64 * 128];   // [d-pair 64][2x kv 64], XOR-swizzled
  __shared__ u16 Plds[8][16][72];              // per-wave P tile, +8 pad
  int qt = (gridDim.x - 1) - blockIdx.x;       // longest blocks first
  int kvh = blockIdx.y, b = blockIdx.z;
  int t = threadIdx.x, lane = t & 63, w = t >> 6;
  int h = kvh * 4 + (w & 3);                   // this wave's head
  int u = w >> 2;                              // q-subtile within block
  int fr = lane & 15, kq = lane >> 4;
  int q0 = qt * 32 + u * 16;                   // this wave's 16 q-rows

  const u16* qbase = QKV + (size_t)(b * S_ + q0 + fr) * QS + (size_t)h * HD;
  bf16x8 qf[4];
#pragma unroll
  for (int kk = 0; kk < 4; ++kk) qf[kk] = as_bf16x8(*(const u16x8*)(qbase + kk * 32 + kq * 8));

  f32x4 o[8] = {};
  float mrow[4] = {-1e30f, -1e30f, -1e30f, -1e30f};
  float lrow[4] = {0.f, 0.f, 0.f, 0.f};

  const u16* kbase = QKV + (size_t)(b * S_) * QS + KOFF + (size_t)kvh * HD;
  const u16* vbase = Vt + (size_t)(b * NKV + kvh) * ((size_t)HD * S_);
  const float scale = 0.08838834764831845f;  // 1/sqrt(128)

  // staging geometry (512 threads): K 64x256B in 16B chunks (2/thread),
  // V 128x128B in 16B chunks (2/thread).
  int krow0 = t >> 4, kc = t & 15;             // K: idx = ps*512 + t
  int vrow0 = t >> 3, vc = t & 7;              // V: idx = ps*512 + t

  int niter = (qt * 32 + 31) / 64 + 1;

  // ---- prologue: load tile 0 into regs
  u16x8 kreg[2], vreg[2];
#pragma unroll
  for (int ps = 0; ps < 2; ++ps) {
    int row = krow0 + ps * 32;
    kreg[ps] = *(const u16x8*)(kbase + (size_t)row * QS + kc * 8);
    int vrow = vrow0 + ps * 64;
    vreg[ps] = *(const u16x8*)(vbase + (size_t)vrow * S_ + vc * 8);
  }

  for (int kt = 0; kt < niter; ++kt) {
    int k0 = kt * 64;
    if (kt) __syncthreads();   // all waves done reading LDS tile kt-1
    // ---- write staged regs -> LDS (16B chunks, chunk' = c ^ (row&15))
#pragma unroll
    for (int ps = 0; ps < 2; ++ps) {
      int row = krow0 + ps * 32;
      *(u16x8*)&Ks[row * 128 + ((kc ^ row) & 15) * 8] = kreg[ps];
      int vrow = vrow0 + ps * 64;                 // d index 0..127
      int vrho = vrow >> 1;                       // d-pair row 0..63
      int vcw  = (vrow & 1) * 8 + vc;             // chunk 0..15
      *(u16x8*)&Vs[vrho * 128 + ((vcw ^ vrho) & 15) * 8] = vreg[ps];
    }
    __syncthreads();           // tile kt visible to all waves
    // ---- T14: issue loads for tile kt+1 (consumed next iteration)
    if (kt + 1 < niter) {
      int k1 = k0 + 64;
#pragma unroll
      for (int ps = 0; ps < 2; ++ps) {
        int row = krow0 + ps * 32;
        kreg[ps] = *(const u16x8*)(kbase + (size_t)(k1 + row) * QS + kc * 8);
        int vrow = vrow0 + ps * 64;
        vreg[ps] = *(const u16x8*)(vbase + (size_t)vrow * S_ + k1 + vc * 8);
      }
    }

    // ---- S = Q K^T from LDS
    f32x4 s[4] = {};
    __builtin_amdgcn_s_setprio(1);
#pragma unroll
    for (int kk = 0; kk < 4; ++kk) {
#pragma unroll
      for (int j = 0; j < 4; ++j) {
        bf16x8 kf = as_bf16x8(*(const u16x8*)&Ks[(j * 16 + fr) * 128 + (((kk * 4 + kq) ^ fr) & 15) * 8]);
        s[j] = __builtin_amdgcn_mfma_f32_16x16x32_bf16(qf[kk], kf, s[j], 0, 0, 0);
      }
    }
    __builtin_amdgcn_s_setprio(0);
    // ---- scale + causal mask + row max
    float mt[4] = {-1e30f, -1e30f, -1e30f, -1e30f};
#pragma unroll
    for (int j = 0; j < 4; ++j) {
      int kv = k0 + j * 16 + fr;
#pragma unroll
      for (int r = 0; r < 4; ++r) {
        int qr = q0 + kq * 4 + r;
        float sv = (kv <= qr) ? s[j][r] * scale : -1e30f;
        s[j][r] = sv;
        mt[r] = fmaxf(mt[r], sv);
      }
    }
#pragma unroll
    for (int off = 1; off < 16; off <<= 1)
#pragma unroll
      for (int r = 0; r < 4; ++r) mt[r] = fmaxf(mt[r], __shfl_xor(mt[r], off, 64));

    float alpha[4], lt[4];
#pragma unroll
    for (int r = 0; r < 4; ++r) {
      float mn = fmaxf(mrow[r], mt[r]);
      alpha[r] = __expf(mrow[r] - mn);
      mrow[r] = mn;
      lt[r] = 0.f;
    }
#pragma unroll
    for (int j = 0; j < 4; ++j)
#pragma unroll
      for (int r = 0; r < 4; ++r) {
        float p = __expf(s[j][r] - mrow[r]);
        s[j][r] = p;
        lt[r] += p;
      }
#pragma unroll
    for (int off = 1; off < 16; off <<= 1)
#pragma unroll
      for (int r = 0; r < 4; ++r) lt[r] += __shfl_xor(lt[r], off, 64);
#pragma unroll
    for (int r = 0; r < 4; ++r) lrow[r] = lrow[r] * alpha[r] + lt[r];
#pragma unroll
    for (int tt = 0; tt < 8; ++tt)
#pragma unroll
      for (int r = 0; r < 4; ++r) o[tt][r] *= alpha[r];

    // ---- P (C-layout) -> per-wave LDS -> A-layout frags
#pragma unroll
    for (int j = 0; j < 4; ++j)
#pragma unroll
      for (int r = 0; r < 4; ++r)
        Plds[w][kq * 4 + r][j * 16 + fr] = f2bf(s[j][r]);

#pragma unroll
    for (int st = 0; st < 2; ++st) {
      bf16x8 pf = as_bf16x8(*(const u16x8*)&Plds[w][fr][st * 32 + kq * 8]);
      __builtin_amdgcn_s_setprio(1);
#pragma unroll
      for (int tt = 0; tt < 8; ++tt) {
        int d = tt * 16 + fr;
        int rho = tt * 8 + (fr >> 1);             // d >> 1
        int c = (fr & 1) * 8 + st * 4 + kq;       // chunk 0..15
        bf16x8 vv = as_bf16x8(*(const u16x8*)&Vs[rho * 128 + ((c ^ rho) & 15) * 8]);
        o[tt] = __builtin_amdgcn_mfma_f32_16x16x32_bf16(pf, vv, o[tt], 0, 0, 0);
      }
      __builtin_amdgcn_s_setprio(0);
    }
  }

  float inv[4];
#pragma unroll
  for (int r = 0; r < 4; ++r) inv[r] = 1.0f / lrow[r];
  u16* obase = O + (size_t)(b * S_ + q0) * H_ + (size_t)h * HD;
#pragma unroll
  for (int tt = 0; tt < 8; ++tt)
#pragma unroll
    for (int r = 0; r < 4; ++r)
      obase[(size_t)(kq * 4 + r) * H_ + tt * 16 + fr] = f2bf(o[tt][r] * inv[r]);
}

// ---------------------------------------------------------------------------
extern "C" void kernel_launch(void* const* d_in, const int* in_sizes, int n_in,
                              void* d_out, int out_size, void* d_ws, size_t ws_size,
                              hipStream_t stream) {
  const float* X  = (const float*)d_in[0];
  const float* Wq = (const float*)d_in[2];
  const float* Wk = (const float*)d_in[3];
  const float* Wv = (const float*)d_in[4];
  const float* Wo = (const float*)d_in[5];
  float* out = (float*)d_out;

  // ws (80 MiB): Wtk 8 | Vt 8 | {Xb -> Ob} 32 | Wtq 32   (bf16)
  // Xb dead after QKV GEMM; Ob first written by flash_attn.
  char* ws = (char*)d_ws;
  u16* Wtk = (u16*)ws;
  u16* Vt  = (u16*)(ws + 8ull  * 1024 * 1024);
  u16* Xb  = (u16*)(ws + 16ull * 1024 * 1024);
  u16* Ob  = (u16*)(ws + 16ull * 1024 * 1024);
  u16* Wtq = (u16*)(ws + 48ull * 1024 * 1024);
  // d_out (64 MiB fp32): QKV bf16 [4096][6144] = 48 MiB | Wtv 8 MiB | spare.
  // Wtv dead after QKV GEMM; QKV dead after flash_attn; final GEMM
  // overwrites all of d_out.
  u16* QKV = (u16*)d_out;
  u16* Wtv = (u16*)((char*)d_out + 48ull * 1024 * 1024);

  dim3 blk(256);
  dim3 blk8(512);

  // X -> bf16 (once; enables global_load_lds staging in all GEMMs)
  conv_bf16<<<dim3((size_t)BS * H_ / 8 / 256), blk, 0, stream>>>(X, Xb);

  // weight transposes (one dispatch for Wq/Wk/Wv)
  conv_transpose_w3<<<dim3(64, 64, 3), blk, 0, stream>>>(Wq, Wk, Wv, Wtq, Wtk, Wtv);

  // QKV = Xb @ [Wq | Wk | Wv]  (one dispatch, 1536 blocks = 6/CU)
  gemm_qkv<<<dim3(32, 48), blk, 0, stream>>>(Xb, Wtq, Wtk, Wtv, QKV);

  // RoPE in-place on Q and K (unified QKV addressing)
  rope_kernel<<<dim3((BS * 40 * 64) / 256), blk, 0, stream>>>(QKV);
  // V -> Vt
  transpose_v<<<dim3(S_ / 64, HD / 64, B_ * NKV), blk, 0, stream>>>(QKV, Vt);
  // attention -> Ob
  flash_attn<<<dim3(S_ / 32, NKV, B_), blk8, 0, stream>>>(QKV, Vt, Ob);
  // out = Ob @ Wo  (fp32 out, overwrites all of d_out)
  conv_transpose_w<<<dim3(64, 64), blk, 0, stream>>>(Wo, Wtq, H_, H_);
  gemm_bt_lds<true><<<dim3(32, 32), blk, 0, stream>>>(Ob, Wtq, out, BS, H_, H_);
}

// Round 7
// 922.213 us; speedup vs baseline: 1.0214x; 1.0214x over previous
//
#include <hip/hip_runtime.h>
#include <stdint.h>

typedef unsigned short u16;

#define B_   2
#define S_   2048
#define H_   4096
#define NH   32
#define NKV  8
#define HD   128
#define KVD  (NKV * HD)   // 1024
#define BS   (B_ * S_)    // 4096
#define QS   6144         // QKV row stride (Q 0..4095 | K 4096..5119 | V 5120..6143)
#define KOFF 4096
#define VOFF 5120

typedef __bf16 bf16x8 __attribute__((ext_vector_type(8)));
typedef u16    u16x8  __attribute__((ext_vector_type(8)));
typedef u16    u16x4  __attribute__((ext_vector_type(4)));
typedef float  f32x4  __attribute__((ext_vector_type(4)));

__device__ __forceinline__ bf16x8 as_bf16x8(u16x8 v) { return __builtin_bit_cast(bf16x8, v); }

__device__ __forceinline__ float bf2f(u16 u) {
  union { uint32_t u; float f; } v; v.u = ((uint32_t)u) << 16; return v.f;
}
// single v_cvt instruction, RNE
__device__ __forceinline__ u16 f2bf(float f) {
  return __builtin_bit_cast(u16, (__bf16)f);
}
// 2^x in one transcendental instruction
__device__ __forceinline__ float fast_exp2(float x) {
  float r;
  asm("v_exp_f32 %0, %1" : "=v"(r) : "v"(x));
  return r;
}

// async global->LDS, 16B per lane; LDS dest must be wave-uniform-base + lane*16
__device__ __forceinline__ void gload_lds16(const void* g, void* l) {
  __builtin_amdgcn_global_load_lds((const __attribute__((address_space(1))) void*)g,
                                   (__attribute__((address_space(3))) void*)l, 16, 0, 0);
}

// ---------------------------------------------------------------------------
// fp32 -> bf16 elementwise (vectorized, 8 elems/thread)
// ---------------------------------------------------------------------------
__global__ __launch_bounds__(256) void conv_bf16(const float* __restrict__ in,
                                                 u16* __restrict__ out) {
  size_t i = ((size_t)blockIdx.x * 256 + threadIdx.x) * 8;
  float4 a = *(const float4*)(in + i);
  float4 b = *(const float4*)(in + i + 4);
  u16x8 h;
  h[0] = f2bf(a.x); h[1] = f2bf(a.y); h[2] = f2bf(a.z); h[3] = f2bf(a.w);
  h[4] = f2bf(b.x); h[5] = f2bf(b.y); h[6] = f2bf(b.z); h[7] = f2bf(b.w);
  *(u16x8*)(out + i) = h;
}

// ---------------------------------------------------------------------------
// Convert + transpose: fp32 in[R][C] -> bf16 out[C][R]; 64x64 tiles.
// ---------------------------------------------------------------------------
__global__ __launch_bounds__(256) void conv_transpose_w(const float* __restrict__ in,
                                                        u16* __restrict__ out,
                                                        int ldi, int ldo) {
  __shared__ u16 tile[64][72];
  int r0 = blockIdx.x * 64, c0 = blockIdx.y * 64;
  int t = threadIdx.x;
  {
    int row = t >> 4, col = (t & 15) * 4;
#pragma unroll
    for (int rep = 0; rep < 4; ++rep) {
      int r = row + rep * 16;
      float4 v = *(const float4*)(in + (size_t)(r0 + r) * ldi + c0 + col);
      u16x4 h;
      h[0] = f2bf(v.x); h[1] = f2bf(v.y); h[2] = f2bf(v.z); h[3] = f2bf(v.w);
      *(u16x4*)&tile[r][col] = h;
    }
  }
  __syncthreads();
  {
    int row = t >> 2, c8 = (t & 3) * 8;
#pragma unroll
    for (int it = 0; it < 2; ++it) {
      int rr = c8 + it * 32;
      u16x8 v;
#pragma unroll
      for (int j = 0; j < 8; ++j) v[j] = tile[rr + j][row];
      *(u16x8*)(out + (size_t)(c0 + row) * ldo + r0 + rr) = v;
    }
  }
}

// ---------------------------------------------------------------------------
// Merged Wq/Wk/Wv convert+transpose (one dispatch): z=0 Wq, z=1 Wk, z=2 Wv.
// ---------------------------------------------------------------------------
__global__ __launch_bounds__(256) void conv_transpose_w3(const float* __restrict__ Wq,
                                                         const float* __restrict__ Wk,
                                                         const float* __restrict__ Wv,
                                                         u16* __restrict__ Wtq,
                                                         u16* __restrict__ Wtk,
                                                         u16* __restrict__ Wtv) {
  __shared__ u16 tile[64][72];
  int z = blockIdx.z;
  if (z > 0 && blockIdx.y >= 16) return;
  const float* in = (z == 0) ? Wq : (z == 1) ? Wk : Wv;
  u16* out        = (z == 0) ? Wtq : (z == 1) ? Wtk : Wtv;
  int ldi = (z == 0) ? H_ : KVD;
  int r0 = blockIdx.x * 64, c0 = blockIdx.y * 64;
  int t = threadIdx.x;
  {
    int row = t >> 4, col = (t & 15) * 4;
#pragma unroll
    for (int rep = 0; rep < 4; ++rep) {
      int r = row + rep * 16;
      float4 v = *(const float4*)(in + (size_t)(r0 + r) * ldi + c0 + col);
      u16x4 h;
      h[0] = f2bf(v.x); h[1] = f2bf(v.y); h[2] = f2bf(v.z); h[3] = f2bf(v.w);
      *(u16x4*)&tile[r][col] = h;
    }
  }
  __syncthreads();
  {
    int row = t >> 2, c8 = (t & 3) * 8;
#pragma unroll
    for (int it = 0; it < 2; ++it) {
      int rr = c8 + it * 32;
      u16x8 v;
#pragma unroll
      for (int j = 0; j < 8; ++j) v[j] = tile[rr + j][row];
      *(u16x8*)(out + (size_t)(c0 + row) * H_ + r0 + rr) = v;
    }
  }
}

// ---------------------------------------------------------------------------
// V transpose (bf16): QKV[b*S_+s][VOFF+kvh*HD+d] -> Vt[((b*NKV+kvh)*HD+d)*S_+s]
// ---------------------------------------------------------------------------
__global__ __launch_bounds__(256) void transpose_v(const u16* __restrict__ QKV,
                                                   u16* __restrict__ Vt) {
  __shared__ u16 tile[64][72];
  int g = blockIdx.z;
  const u16* in = QKV + (size_t)(g >> 3) * ((size_t)S_ * QS) + VOFF + (size_t)(g & 7) * HD;
  u16* out = Vt + (size_t)g * ((size_t)HD * S_);
  int r0 = blockIdx.x * 64, c0 = blockIdx.y * 64;
  int t = threadIdx.x;
  int row = t >> 2, c8 = (t & 3) * 8;
#pragma unroll
  for (int it = 0; it < 2; ++it) {
    int col = c8 + it * 32;
    *(u16x8*)&tile[row][col] = *(const u16x8*)(in + (size_t)(r0 + row) * QS + c0 + col);
  }
  __syncthreads();
#pragma unroll
  for (int it = 0; it < 2; ++it) {
    int rr = c8 + it * 32;
    u16x8 v;
#pragma unroll
    for (int j = 0; j < 8; ++j) v[j] = tile[rr + j][row];
    *(u16x8*)(out + (size_t)(c0 + row) * S_ + r0 + rr) = v;
  }
}

// ---------------------------------------------------------------------------
// C[M][N] = A[M][K] @ Bt[N][K]^T.  A bf16, C bf16 or fp32.  m97 structure.
// ---------------------------------------------------------------------------
template <bool C_F32>
__global__ __launch_bounds__(256) void gemm_bt_lds(const u16* __restrict__ A,
                                                   const u16* __restrict__ Bt,
                                                   void* __restrict__ Cp,
                                                   int M, int N, int K) {
  __shared__ __align__(16) u16 lsA[128][32];
  __shared__ __align__(16) u16 lsB[128][32];
  int t = threadIdx.x;
  int lane = t & 63;
  int w = t >> 6;
  int wm = (w >> 1) * 64, wn = (w & 1) * 64;
  int bm = blockIdx.x * 128, bn = blockIdx.y * 128;
  int fr = lane & 15, kq = lane >> 4;
  f32x4 acc[4][4] = {};

  int sr = t >> 2, sc = (t & 3) * 8;
  const u16* Ar0 = A + (size_t)(bm + sr) * K + sc;
  const u16* Ar1 = A + (size_t)(bm + sr + 64) * K + sc;
  const u16* Br0 = Bt + (size_t)(bn + sr) * K + sc;
  const u16* Br1 = Bt + (size_t)(bn + sr + 64) * K + sc;
  u16* lA0 = &lsA[sr][sc];
  u16* lA1 = &lsA[sr + 64][sc];
  u16* lB0 = &lsB[sr][sc];
  u16* lB1 = &lsB[sr + 64][sc];

  for (int k0 = 0; k0 < K; k0 += 32) {
    gload_lds16(Ar0 + k0, lA0);
    gload_lds16(Ar1 + k0, lA1);
    gload_lds16(Br0 + k0, lB0);
    gload_lds16(Br1 + k0, lB1);
    __syncthreads();
    bf16x8 af[4], bfr[4];
#pragma unroll
    for (int i = 0; i < 4; ++i) af[i] = as_bf16x8(*(const u16x8*)&lsA[wm + i * 16 + fr][kq * 8]);
#pragma unroll
    for (int j = 0; j < 4; ++j) bfr[j] = as_bf16x8(*(const u16x8*)&lsB[wn + j * 16 + fr][kq * 8]);
#pragma unroll
    for (int i = 0; i < 4; ++i)
#pragma unroll
      for (int j = 0; j < 4; ++j)
        acc[i][j] = __builtin_amdgcn_mfma_f32_16x16x32_bf16(af[i], bfr[j], acc[i][j], 0, 0, 0);
    __syncthreads();
  }
#pragma unroll
  for (int i = 0; i < 4; ++i)
#pragma unroll
    for (int j = 0; j < 4; ++j)
#pragma unroll
      for (int r = 0; r < 4; ++r) {
        int row = bm + wm + i * 16 + kq * 4 + r;
        int col = bn + wn + j * 16 + fr;
        if (C_F32) ((float*)Cp)[(size_t)row * N + col] = acc[i][j][r];
        else       ((u16*)Cp)[(size_t)row * N + col] = f2bf(acc[i][j][r]);
      }
}

// ---------------------------------------------------------------------------
// Fused QKV projection: C[4096][6144] = Xb @ [Wq | Wk | Wv].
// ---------------------------------------------------------------------------
__global__ __launch_bounds__(256) void gemm_qkv(const u16* __restrict__ A,
                                                const u16* __restrict__ Wtq,
                                                const u16* __restrict__ Wtk,
                                                const u16* __restrict__ Wtv,
                                                u16* __restrict__ C) {
  const int K = H_;
  __shared__ __align__(16) u16 lsA[128][32];
  __shared__ __align__(16) u16 lsB[128][32];
  int t = threadIdx.x;
  int lane = t & 63;
  int w = t >> 6;
  int wm = (w >> 1) * 64, wn = (w & 1) * 64;
  int bm = blockIdx.x * 128;
  int by = blockIdx.y;                 // 0..47
  const u16* Bt; int bnl;
  if (by < 32)      { Bt = Wtq; bnl = by * 128; }
  else if (by < 40) { Bt = Wtk; bnl = (by - 32) * 128; }
  else              { Bt = Wtv; bnl = (by - 40) * 128; }
  int bn = by * 128;                   // global col in QKV space
  int fr = lane & 15, kq = lane >> 4;
  f32x4 acc[4][4] = {};

  int sr = t >> 2, sc = (t & 3) * 8;
  const u16* Ar0 = A + (size_t)(bm + sr) * K + sc;
  const u16* Ar1 = Ar0 + (size_t)64 * K;
  const u16* Br0 = Bt + (size_t)(bnl + sr) * K + sc;
  const u16* Br1 = Br0 + (size_t)64 * K;
  u16* lA0 = &lsA[sr][sc];
  u16* lA1 = &lsA[sr + 64][sc];
  u16* lB0 = &lsB[sr][sc];
  u16* lB1 = &lsB[sr + 64][sc];

  for (int k0 = 0; k0 < K; k0 += 32) {
    gload_lds16(Ar0 + k0, lA0);
    gload_lds16(Ar1 + k0, lA1);
    gload_lds16(Br0 + k0, lB0);
    gload_lds16(Br1 + k0, lB1);
    __syncthreads();
    bf16x8 af[4], bfr[4];
#pragma unroll
    for (int i = 0; i < 4; ++i) af[i] = as_bf16x8(*(const u16x8*)&lsA[wm + i * 16 + fr][kq * 8]);
#pragma unroll
    for (int j = 0; j < 4; ++j) bfr[j] = as_bf16x8(*(const u16x8*)&lsB[wn + j * 16 + fr][kq * 8]);
#pragma unroll
    for (int i = 0; i < 4; ++i)
#pragma unroll
      for (int j = 0; j < 4; ++j)
        acc[i][j] = __builtin_amdgcn_mfma_f32_16x16x32_bf16(af[i], bfr[j], acc[i][j], 0, 0, 0);
    __syncthreads();
  }
#pragma unroll
  for (int i = 0; i < 4; ++i)
#pragma unroll
    for (int j = 0; j < 4; ++j)
#pragma unroll
      for (int r = 0; r < 4; ++r) {
        int row = bm + wm + i * 16 + kq * 4 + r;
        int col = bn + wn + j * 16 + fr;
        C[(size_t)row * QS + col] = f2bf(acc[i][j][r]);
      }
}

// ---------------------------------------------------------------------------
// RoPE in-place on QKV (heads hh=0..39 at col hh*128 — unified addressing).
// ---------------------------------------------------------------------------
__global__ __launch_bounds__(256) void rope_kernel(u16* __restrict__ QKV) {
  int idx = blockIdx.x * 256 + threadIdx.x;  // BS * 40 * 64 total
  int j = idx & 63;
  int rem = idx >> 6;
  int hh = rem % 40;
  int tok = rem / 40;
  float p = (float)(tok % S_);
  float freq = __expf((float)j * (-9.210340371976184f / 64.0f));  // 10000^(-j/64)
  float sn, cs;
  __sincosf(p * freq, &sn, &cs);
  u16* base = QKV + (size_t)tok * QS + (size_t)hh * HD;
  float x1 = bf2f(base[j]), x2 = bf2f(base[j + 64]);
  base[j]      = f2bf(x1 * cs - x2 * sn);
  base[j + 64] = f2bf(x2 * cs + x1 * sn);
}

// ---------------------------------------------------------------------------
// Flash attention, causal, GQA(4).
// This round: V back to padded [128][72] (round-5 layout — measured fastest;
// bank-conflict counter proven off-critical-path in r4/r6 A/B), causal mask
// hoisted to diagonal tiles only, raw-domain max + single-instruction
// v_exp_f32 softmax (scale folded into exp2 constant), T13 defer-max
// (skip alpha/rescale when tile max growth <= 8/scale).
// grid: (S_/32, NKV, B_), 8 waves/block; wave w: head kvh*4+(w&3),
// q-subtile u=(w>>2).  K/V staged in LDS once per iter, shared by 8 waves.
// T14 async-STAGE: tile kt+1 loaded to regs after staging barrier.
// ---------------------------------------------------------------------------
__global__ __launch_bounds__(512) void flash_attn(const u16* __restrict__ QKV,
                                                  const u16* __restrict__ Vt,
                                                  u16* __restrict__ O) {
  __shared__ __align__(16) u16 Ks[64 * 128];   // [kv 64][d 128], XOR-swizzled
  __shared__ __align__(16) u16 Vs[128][72];    // [d 128][kv 64+8 pad], linear
  __shared__ u16 Plds[8][16][72];              // per-wave P tile, +8 pad
  int qt = (gridDim.x - 1) - blockIdx.x;       // longest blocks first
  int kvh = blockIdx.y, b = blockIdx.z;
  int t = threadIdx.x, lane = t & 63, w = t >> 6;
  int h = kvh * 4 + (w & 3);                   // this wave's head
  int u = w >> 2;                              // q-subtile within block
  int fr = lane & 15, kq = lane >> 4;
  int q0 = qt * 32 + u * 16;                   // this wave's 16 q-rows

  const u16* qbase = QKV + (size_t)(b * S_ + q0 + fr) * QS + (size_t)h * HD;
  bf16x8 qf[4];
#pragma unroll
  for (int kk = 0; kk < 4; ++kk) qf[kk] = as_bf16x8(*(const u16x8*)(qbase + kk * 32 + kq * 8));

  f32x4 o[8] = {};
  float mrow[4] = {-1e30f, -1e30f, -1e30f, -1e30f};
  float lrow[4] = {0.f, 0.f, 0.f, 0.f};

  const u16* kbase = QKV + (size_t)(b * S_) * QS + KOFF + (size_t)kvh * HD;
  const u16* vbase = Vt + (size_t)(b * NKV + kvh) * ((size_t)HD * S_);
  // exp2 constant: scale * log2(e) = (1/sqrt(128)) * 1.4426950408889634
  const float SC2 = 0.12751745f;
  const float THR = 90.5f;                     // 8 / scale (raw-domain defer-max)

  // staging geometry (512 threads): K 64x256B in 16B chunks (2/thread),
  // V 128x128B in 16B chunks (2/thread), written straight to padded rows.
  int krow0 = t >> 4, kc = t & 15;             // K: idx = ps*512 + t
  int vrow0 = t >> 3, vc = t & 7;              // V: idx = ps*512 + t

  int niter = (qt * 32 + 31) / 64 + 1;

  // ---- prologue: load tile 0 into regs
  u16x8 kreg[2], vreg[2];
#pragma unroll
  for (int ps = 0; ps < 2; ++ps) {
    int row = krow0 + ps * 32;
    kreg[ps] = *(const u16x8*)(kbase + (size_t)row * QS + kc * 8);
    int vrow = vrow0 + ps * 64;
    vreg[ps] = *(const u16x8*)(vbase + (size_t)vrow * S_ + vc * 8);
  }

  for (int kt = 0; kt < niter; ++kt) {
    int k0 = kt * 64;
    if (kt) __syncthreads();   // all waves done reading LDS tile kt-1
    // ---- write staged regs -> LDS (K: 16B chunks, chunk' = c ^ (row&15))
#pragma unroll
    for (int ps = 0; ps < 2; ++ps) {
      int row = krow0 + ps * 32;
      *(u16x8*)&Ks[row * 128 + ((kc ^ row) & 15) * 8] = kreg[ps];
      int vrow = vrow0 + ps * 64;
      *(u16x8*)&Vs[vrow][vc * 8] = vreg[ps];
    }
    __syncthreads();           // tile kt visible to all waves
    // ---- T14: issue loads for tile kt+1 (consumed next iteration)
    if (kt + 1 < niter) {
      int k1 = k0 + 64;
#pragma unroll
      for (int ps = 0; ps < 2; ++ps) {
        int row = krow0 + ps * 32;
        kreg[ps] = *(const u16x8*)(kbase + (size_t)(k1 + row) * QS + kc * 8);
        int vrow = vrow0 + ps * 64;
        vreg[ps] = *(const u16x8*)(vbase + (size_t)vrow * S_ + k1 + vc * 8);
      }
    }

    // ---- S = Q K^T from LDS (raw scores; scale folded into exp2 const)
    f32x4 s[4] = {};
    __builtin_amdgcn_s_setprio(1);
#pragma unroll
    for (int kk = 0; kk < 4; ++kk) {
#pragma unroll
      for (int j = 0; j < 4; ++j) {
        bf16x8 kf = as_bf16x8(*(const u16x8*)&Ks[(j * 16 + fr) * 128 + (((kk * 4 + kq) ^ fr) & 15) * 8]);
        s[j] = __builtin_amdgcn_mfma_f32_16x16x32_bf16(qf[kk], kf, s[j], 0, 0, 0);
      }
    }
    __builtin_amdgcn_s_setprio(0);

    // ---- causal mask only on diagonal tiles (wave-uniform branch)
    float mt[4] = {-1e30f, -1e30f, -1e30f, -1e30f};
    if (k0 + 63 > q0) {
#pragma unroll
      for (int j = 0; j < 4; ++j) {
        int kv = k0 + j * 16 + fr;
#pragma unroll
        for (int r = 0; r < 4; ++r) {
          int qr = q0 + kq * 4 + r;
          float sv = (kv <= qr) ? s[j][r] : -1e30f;
          s[j][r] = sv;
          mt[r] = fmaxf(mt[r], sv);
        }
      }
    } else {
#pragma unroll
      for (int j = 0; j < 4; ++j)
#pragma unroll
        for (int r = 0; r < 4; ++r) mt[r] = fmaxf(mt[r], s[j][r]);
    }
#pragma unroll
    for (int off = 1; off < 16; off <<= 1)
#pragma unroll
      for (int r = 0; r < 4; ++r) mt[r] = fmaxf(mt[r], __shfl_xor(mt[r], off, 64));

    // ---- T13 defer-max: rescale only when max growth exceeds threshold
    float g = fmaxf(fmaxf(mt[0] - mrow[0], mt[1] - mrow[1]),
                    fmaxf(mt[2] - mrow[2], mt[3] - mrow[3]));
    if (!__all(g <= THR)) {
#pragma unroll
      for (int r = 0; r < 4; ++r) {
        float mn = fmaxf(mrow[r], mt[r]);
        float a = fast_exp2((mrow[r] - mn) * SC2);
        mrow[r] = mn;
        lrow[r] *= a;
#pragma unroll
        for (int tt = 0; tt < 8; ++tt) o[tt][r] *= a;
      }
    }

    // ---- P = exp2((s - m) * SC2), row sums
    float lt[4] = {0.f, 0.f, 0.f, 0.f};
#pragma unroll
    for (int j = 0; j < 4; ++j)
#pragma unroll
      for (int r = 0; r < 4; ++r) {
        float p = fast_exp2((s[j][r] - mrow[r]) * SC2);
        s[j][r] = p;
        lt[r] += p;
      }
#pragma unroll
    for (int off = 1; off < 16; off <<= 1)
#pragma unroll
      for (int r = 0; r < 4; ++r) lt[r] += __shfl_xor(lt[r], off, 64);
#pragma unroll
    for (int r = 0; r < 4; ++r) lrow[r] += lt[r];

    // ---- P (C-layout) -> per-wave LDS -> A-layout frags
#pragma unroll
    for (int j = 0; j < 4; ++j)
#pragma unroll
      for (int r = 0; r < 4; ++r)
        Plds[w][kq * 4 + r][j * 16 + fr] = f2bf(s[j][r]);

#pragma unroll
    for (int st = 0; st < 2; ++st) {
      bf16x8 pf = as_bf16x8(*(const u16x8*)&Plds[w][fr][st * 32 + kq * 8]);
      __builtin_amdgcn_s_setprio(1);
#pragma unroll
      for (int tt = 0; tt < 8; ++tt) {
        bf16x8 vv = as_bf16x8(*(const u16x8*)&Vs[tt * 16 + fr][st * 32 + kq * 8]);
        o[tt] = __builtin_amdgcn_mfma_f32_16x16x32_bf16(pf, vv, o[tt], 0, 0, 0);
      }
      __builtin_amdgcn_s_setprio(0);
    }
  }

  float inv[4];
#pragma unroll
  for (int r = 0; r < 4; ++r) inv[r] = 1.0f / lrow[r];
  u16* obase = O + (size_t)(b * S_ + q0) * H_ + (size_t)h * HD;
#pragma unroll
  for (int tt = 0; tt < 8; ++tt)
#pragma unroll
    for (int r = 0; r < 4; ++r)
      obase[(size_t)(kq * 4 + r) * H_ + tt * 16 + fr] = f2bf(o[tt][r] * inv[r]);
}

// ---------------------------------------------------------------------------
extern "C" void kernel_launch(void* const* d_in, const int* in_sizes, int n_in,
                              void* d_out, int out_size, void* d_ws, size_t ws_size,
                              hipStream_t stream) {
  const float* X  = (const float*)d_in[0];
  const float* Wq = (const float*)d_in[2];
  const float* Wk = (const float*)d_in[3];
  const float* Wv = (const float*)d_in[4];
  const float* Wo = (const float*)d_in[5];
  float* out = (float*)d_out;

  // ws (80 MiB): Wtk 8 | Vt 8 | {Xb -> Ob} 32 | Wtq 32   (bf16)
  char* ws = (char*)d_ws;
  u16* Wtk = (u16*)ws;
  u16* Vt  = (u16*)(ws + 8ull  * 1024 * 1024);
  u16* Xb  = (u16*)(ws + 16ull * 1024 * 1024);
  u16* Ob  = (u16*)(ws + 16ull * 1024 * 1024);
  u16* Wtq = (u16*)(ws + 48ull * 1024 * 1024);
  // d_out (64 MiB fp32): QKV bf16 [4096][6144] = 48 MiB | Wtv 8 MiB | spare.
  u16* QKV = (u16*)d_out;
  u16* Wtv = (u16*)((char*)d_out + 48ull * 1024 * 1024);

  dim3 blk(256);
  dim3 blk8(512);

  // X -> bf16 (once; enables global_load_lds staging in all GEMMs)
  conv_bf16<<<dim3((size_t)BS * H_ / 8 / 256), blk, 0, stream>>>(X, Xb);

  // weight transposes (one dispatch for Wq/Wk/Wv)
  conv_transpose_w3<<<dim3(64, 64, 3), blk, 0, stream>>>(Wq, Wk, Wv, Wtq, Wtk, Wtv);

  // QKV = Xb @ [Wq | Wk | Wv]  (one dispatch, 1536 blocks = 6/CU)
  gemm_qkv<<<dim3(32, 48), blk, 0, stream>>>(Xb, Wtq, Wtk, Wtv, QKV);

  // RoPE in-place on Q and K (unified QKV addressing)
  rope_kernel<<<dim3((BS * 40 * 64) / 256), blk, 0, stream>>>(QKV);
  // V -> Vt
  transpose_v<<<dim3(S_ / 64, HD / 64, B_ * NKV), blk, 0, stream>>>(QKV, Vt);
  // attention -> Ob
  flash_attn<<<dim3(S_ / 32, NKV, B_), blk8, 0, stream>>>(QKV, Vt, Ob);
  // out = Ob @ Wo  (fp32 out, overwrites all of d_out)
  conv_transpose_w<<<dim3(64, 64), blk, 0, stream>>>(Wo, Wtq, H_, H_);
  gemm_bt_lds<true><<<dim3(32, 32), blk, 0, stream>>>(Ob, Wtq, out, BS, H_, H_);
}

// Round 9
// 858.833 us; speedup vs baseline: 1.0968x; 1.0738x over previous
//
#include <hip/hip_runtime.h>
#include <stdint.h>

typedef unsigned short u16;

#define B_   2
#define S_   2048
#define H_   4096
#define NH   32
#define NKV  8
#define HD   128
#define KVD  (NKV * HD)   // 1024
#define BS   (B_ * S_)    // 4096
#define QS   6144         // QKV row stride (Q 0..4095 | K 4096..5119 | V 5120..6143)
#define KOFF 4096
#define VOFF 5120

typedef __bf16 bf16x8 __attribute__((ext_vector_type(8)));
typedef u16    u16x8  __attribute__((ext_vector_type(8)));
typedef u16    u16x4  __attribute__((ext_vector_type(4)));
typedef float  f32x4  __attribute__((ext_vector_type(4)));

__device__ __forceinline__ bf16x8 as_bf16x8(u16x8 v) { return __builtin_bit_cast(bf16x8, v); }

__device__ __forceinline__ float bf2f(u16 u) {
  union { uint32_t u; float f; } v; v.u = ((uint32_t)u) << 16; return v.f;
}
// single v_cvt instruction, RNE
__device__ __forceinline__ u16 f2bf(float f) {
  return __builtin_bit_cast(u16, (__bf16)f);
}
// 2^x in one transcendental instruction
__device__ __forceinline__ float fast_exp2(float x) {
  float r;
  asm("v_exp_f32 %0, %1" : "=v"(r) : "v"(x));
  return r;
}

// async global->LDS, 16B per lane; LDS dest must be wave-uniform-base + lane*16
__device__ __forceinline__ void gload_lds16(const void* g, void* l) {
  __builtin_amdgcn_global_load_lds((const __attribute__((address_space(1))) void*)g,
                                   (__attribute__((address_space(3))) void*)l, 16, 0, 0);
}

// ---------------------------------------------------------------------------
// fp32 -> bf16 elementwise (vectorized, 8 elems/thread)
// ---------------------------------------------------------------------------
__global__ __launch_bounds__(256) void conv_bf16(const float* __restrict__ in,
                                                 u16* __restrict__ out) {
  size_t i = ((size_t)blockIdx.x * 256 + threadIdx.x) * 8;
  float4 a = *(const float4*)(in + i);
  float4 b = *(const float4*)(in + i + 4);
  u16x8 h;
  h[0] = f2bf(a.x); h[1] = f2bf(a.y); h[2] = f2bf(a.z); h[3] = f2bf(a.w);
  h[4] = f2bf(b.x); h[5] = f2bf(b.y); h[6] = f2bf(b.z); h[7] = f2bf(b.w);
  *(u16x8*)(out + i) = h;
}

// ---------------------------------------------------------------------------
// Convert + transpose: fp32 in[R][C] -> bf16 out[C][R]; 64x64 tiles.
// ---------------------------------------------------------------------------
__global__ __launch_bounds__(256) void conv_transpose_w(const float* __restrict__ in,
                                                        u16* __restrict__ out,
                                                        int ldi, int ldo) {
  __shared__ u16 tile[64][72];
  int r0 = blockIdx.x * 64, c0 = blockIdx.y * 64;
  int t = threadIdx.x;
  {
    int row = t >> 4, col = (t & 15) * 4;
#pragma unroll
    for (int rep = 0; rep < 4; ++rep) {
      int r = row + rep * 16;
      float4 v = *(const float4*)(in + (size_t)(r0 + r) * ldi + c0 + col);
      u16x4 h;
      h[0] = f2bf(v.x); h[1] = f2bf(v.y); h[2] = f2bf(v.z); h[3] = f2bf(v.w);
      *(u16x4*)&tile[r][col] = h;
    }
  }
  __syncthreads();
  {
    int row = t >> 2, c8 = (t & 3) * 8;
#pragma unroll
    for (int it = 0; it < 2; ++it) {
      int rr = c8 + it * 32;
      u16x8 v;
#pragma unroll
      for (int j = 0; j < 8; ++j) v[j] = tile[rr + j][row];
      *(u16x8*)(out + (size_t)(c0 + row) * ldo + r0 + rr) = v;
    }
  }
}

// ---------------------------------------------------------------------------
// Merged Wq/Wk/Wv convert+transpose (one dispatch): z=0 Wq, z=1 Wk, z=2 Wv.
// ---------------------------------------------------------------------------
__global__ __launch_bounds__(256) void conv_transpose_w3(const float* __restrict__ Wq,
                                                         const float* __restrict__ Wk,
                                                         const float* __restrict__ Wv,
                                                         u16* __restrict__ Wtq,
                                                         u16* __restrict__ Wtk,
                                                         u16* __restrict__ Wtv) {
  __shared__ u16 tile[64][72];
  int z = blockIdx.z;
  if (z > 0 && blockIdx.y >= 16) return;
  const float* in = (z == 0) ? Wq : (z == 1) ? Wk : Wv;
  u16* out        = (z == 0) ? Wtq : (z == 1) ? Wtk : Wtv;
  int ldi = (z == 0) ? H_ : KVD;
  int r0 = blockIdx.x * 64, c0 = blockIdx.y * 64;
  int t = threadIdx.x;
  {
    int row = t >> 4, col = (t & 15) * 4;
#pragma unroll
    for (int rep = 0; rep < 4; ++rep) {
      int r = row + rep * 16;
      float4 v = *(const float4*)(in + (size_t)(r0 + r) * ldi + c0 + col);
      u16x4 h;
      h[0] = f2bf(v.x); h[1] = f2bf(v.y); h[2] = f2bf(v.z); h[3] = f2bf(v.w);
      *(u16x4*)&tile[r][col] = h;
    }
  }
  __syncthreads();
  {
    int row = t >> 2, c8 = (t & 3) * 8;
#pragma unroll
    for (int it = 0; it < 2; ++it) {
      int rr = c8 + it * 32;
      u16x8 v;
#pragma unroll
      for (int j = 0; j < 8; ++j) v[j] = tile[rr + j][row];
      *(u16x8*)(out + (size_t)(c0 + row) * H_ + r0 + rr) = v;
    }
  }
}

// ---------------------------------------------------------------------------
// V transpose (bf16): QKV[b*S_+s][VOFF+kvh*HD+d] -> Vt[((b*NKV+kvh)*HD+d)*S_+s]
// ---------------------------------------------------------------------------
__global__ __launch_bounds__(256) void transpose_v(const u16* __restrict__ QKV,
                                                   u16* __restrict__ Vt) {
  __shared__ u16 tile[64][72];
  int g = blockIdx.z;
  const u16* in = QKV + (size_t)(g >> 3) * ((size_t)S_ * QS) + VOFF + (size_t)(g & 7) * HD;
  u16* out = Vt + (size_t)g * ((size_t)HD * S_);
  int r0 = blockIdx.x * 64, c0 = blockIdx.y * 64;
  int t = threadIdx.x;
  int row = t >> 2, c8 = (t & 3) * 8;
#pragma unroll
  for (int it = 0; it < 2; ++it) {
    int col = c8 + it * 32;
    *(u16x8*)&tile[row][col] = *(const u16x8*)(in + (size_t)(r0 + row) * QS + c0 + col);
  }
  __syncthreads();
#pragma unroll
  for (int it = 0; it < 2; ++it) {
    int rr = c8 + it * 32;
    u16x8 v;
#pragma unroll
    for (int j = 0; j < 8; ++j) v[j] = tile[rr + j][row];
    *(u16x8*)(out + (size_t)(c0 + row) * S_ + r0 + rr) = v;
  }
}

// ---------------------------------------------------------------------------
// C[M][N] = A[M][K] @ Bt[N][K]^T.  A bf16, C bf16 or fp32.  m97 structure.
// ---------------------------------------------------------------------------
template <bool C_F32>
__global__ __launch_bounds__(256) void gemm_bt_lds(const u16* __restrict__ A,
                                                   const u16* __restrict__ Bt,
                                                   void* __restrict__ Cp,
                                                   int M, int N, int K) {
  __shared__ __align__(16) u16 lsA[128][32];
  __shared__ __align__(16) u16 lsB[128][32];
  int t = threadIdx.x;
  int lane = t & 63;
  int w = t >> 6;
  int wm = (w >> 1) * 64, wn = (w & 1) * 64;
  int bm = blockIdx.x * 128, bn = blockIdx.y * 128;
  int fr = lane & 15, kq = lane >> 4;
  f32x4 acc[4][4] = {};

  int sr = t >> 2, sc = (t & 3) * 8;
  const u16* Ar0 = A + (size_t)(bm + sr) * K + sc;
  const u16* Ar1 = A + (size_t)(bm + sr + 64) * K + sc;
  const u16* Br0 = Bt + (size_t)(bn + sr) * K + sc;
  const u16* Br1 = Bt + (size_t)(bn + sr + 64) * K + sc;
  u16* lA0 = &lsA[sr][sc];
  u16* lA1 = &lsA[sr + 64][sc];
  u16* lB0 = &lsB[sr][sc];
  u16* lB1 = &lsB[sr + 64][sc];

  for (int k0 = 0; k0 < K; k0 += 32) {
    gload_lds16(Ar0 + k0, lA0);
    gload_lds16(Ar1 + k0, lA1);
    gload_lds16(Br0 + k0, lB0);
    gload_lds16(Br1 + k0, lB1);
    __syncthreads();
    bf16x8 af[4], bfr[4];
#pragma unroll
    for (int i = 0; i < 4; ++i) af[i] = as_bf16x8(*(const u16x8*)&lsA[wm + i * 16 + fr][kq * 8]);
#pragma unroll
    for (int j = 0; j < 4; ++j) bfr[j] = as_bf16x8(*(const u16x8*)&lsB[wn + j * 16 + fr][kq * 8]);
#pragma unroll
    for (int i = 0; i < 4; ++i)
#pragma unroll
      for (int j = 0; j < 4; ++j)
        acc[i][j] = __builtin_amdgcn_mfma_f32_16x16x32_bf16(af[i], bfr[j], acc[i][j], 0, 0, 0);
    __syncthreads();
  }
#pragma unroll
  for (int i = 0; i < 4; ++i)
#pragma unroll
    for (int j = 0; j < 4; ++j)
#pragma unroll
      for (int r = 0; r < 4; ++r) {
        int row = bm + wm + i * 16 + kq * 4 + r;
        int col = bn + wn + j * 16 + fr;
        if (C_F32) ((float*)Cp)[(size_t)row * N + col] = acc[i][j][r];
        else       ((u16*)Cp)[(size_t)row * N + col] = f2bf(acc[i][j][r]);
      }
}

// ---------------------------------------------------------------------------
// Fused QKV projection: C[4096][6144] = Xb @ [Wq | Wk | Wv].
// ---------------------------------------------------------------------------
__global__ __launch_bounds__(256) void gemm_qkv(const u16* __restrict__ A,
                                                const u16* __restrict__ Wtq,
                                                const u16* __restrict__ Wtk,
                                                const u16* __restrict__ Wtv,
                                                u16* __restrict__ C) {
  const int K = H_;
  __shared__ __align__(16) u16 lsA[128][32];
  __shared__ __align__(16) u16 lsB[128][32];
  int t = threadIdx.x;
  int lane = t & 63;
  int w = t >> 6;
  int wm = (w >> 1) * 64, wn = (w & 1) * 64;
  int bm = blockIdx.x * 128;
  int by = blockIdx.y;                 // 0..47
  const u16* Bt; int bnl;
  if (by < 32)      { Bt = Wtq; bnl = by * 128; }
  else if (by < 40) { Bt = Wtk; bnl = (by - 32) * 128; }
  else              { Bt = Wtv; bnl = (by - 40) * 128; }
  int bn = by * 128;                   // global col in QKV space
  int fr = lane & 15, kq = lane >> 4;
  f32x4 acc[4][4] = {};

  int sr = t >> 2, sc = (t & 3) * 8;
  const u16* Ar0 = A + (size_t)(bm + sr) * K + sc;
  const u16* Ar1 = Ar0 + (size_t)64 * K;
  const u16* Br0 = Bt + (size_t)(bnl + sr) * K + sc;
  const u16* Br1 = Br0 + (size_t)64 * K;
  u16* lA0 = &lsA[sr][sc];
  u16* lA1 = &lsA[sr + 64][sc];
  u16* lB0 = &lsB[sr][sc];
  u16* lB1 = &lsB[sr + 64][sc];

  for (int k0 = 0; k0 < K; k0 += 32) {
    gload_lds16(Ar0 + k0, lA0);
    gload_lds16(Ar1 + k0, lA1);
    gload_lds16(Br0 + k0, lB0);
    gload_lds16(Br1 + k0, lB1);
    __syncthreads();
    bf16x8 af[4], bfr[4];
#pragma unroll
    for (int i = 0; i < 4; ++i) af[i] = as_bf16x8(*(const u16x8*)&lsA[wm + i * 16 + fr][kq * 8]);
#pragma unroll
    for (int j = 0; j < 4; ++j) bfr[j] = as_bf16x8(*(const u16x8*)&lsB[wn + j * 16 + fr][kq * 8]);
#pragma unroll
    for (int i = 0; i < 4; ++i)
#pragma unroll
      for (int j = 0; j < 4; ++j)
        acc[i][j] = __builtin_amdgcn_mfma_f32_16x16x32_bf16(af[i], bfr[j], acc[i][j], 0, 0, 0);
    __syncthreads();
  }
#pragma unroll
  for (int i = 0; i < 4; ++i)
#pragma unroll
    for (int j = 0; j < 4; ++j)
#pragma unroll
      for (int r = 0; r < 4; ++r) {
        int row = bm + wm + i * 16 + kq * 4 + r;
        int col = bn + wn + j * 16 + fr;
        C[(size_t)row * QS + col] = f2bf(acc[i][j][r]);
      }
}

// ---------------------------------------------------------------------------
// RoPE in-place on QKV (heads hh=0..39 at col hh*128 — unified addressing).
// ---------------------------------------------------------------------------
__global__ __launch_bounds__(256) void rope_kernel(u16* __restrict__ QKV) {
  int idx = blockIdx.x * 256 + threadIdx.x;  // BS * 40 * 64 total
  int j = idx & 63;
  int rem = idx >> 6;
  int hh = rem % 40;
  int tok = rem / 40;
  float p = (float)(tok % S_);
  float freq = __expf((float)j * (-9.210340371976184f / 64.0f));  // 10000^(-j/64)
  float sn, cs;
  __sincosf(p * freq, &sn, &cs);
  u16* base = QKV + (size_t)tok * QS + (size_t)hh * HD;
  float x1 = bf2f(base[j]), x2 = bf2f(base[j + 64]);
  base[j]      = f2bf(x1 * cs - x2 * sn);
  base[j + 64] = f2bf(x2 * cs + x1 * sn);
}

// ---------------------------------------------------------------------------
// Flash attention, causal, GQA(4).
// SWAPPED QK^T — s[j] = mfma(kf, qf) computes S^T with the SAME operand
// registers (A-frag of K == B-frag of K^T, ditto Q; fragment-layout
// identity).  Lane (fr,kq) holds S[q = q0+fr][k = k0+j*16+kq*4+r]:
//   * row max/sum: in-lane tree over 16 regs + 2 shfl_xor (off 16,32)
//   * softmax state scalar (mrow/lrow); o-rescale alphas via 4 uniform shfl
//   * P-store: 4 x ds_write_b64; Plds READ layout unchanged -> PV +
//     epilogue identical to verified code.
// V tile: padded [128][72] (r5 best).  K tile: XOR-swizzled.  T14 async-
// stage, defer-max (raw-domain THR), diagonal-only mask, setprio on MFMA.
// grid: (S_/32, NKV, B_), 8 waves/block, qt reversed (longest first).
// ---------------------------------------------------------------------------
__global__ __launch_bounds__(512) void flash_attn(const u16* __restrict__ QKV,
                                                  const u16* __restrict__ Vt,
                                                  u16* __restrict__ O) {
  __shared__ __align__(16) u16 Ks[64 * 128];   // [kv 64][d 128], XOR-swizzled
  __shared__ __align__(16) u16 Vs[128][72];    // [d 128][kv 64+8 pad], linear
  __shared__ __align__(16) u16 Plds[8][16][72];// per-wave P tile, +8 pad
  int qt = (gridDim.x - 1) - blockIdx.x;       // longest blocks first
  int kvh = blockIdx.y, b = blockIdx.z;
  int t = threadIdx.x, lane = t & 63, w = t >> 6;
  int h = kvh * 4 + (w & 3);                   // this wave's head
  int u = w >> 2;                              // q-subtile within block
  int fr = lane & 15, kq = lane >> 4;
  int q0 = qt * 32 + u * 16;                   // this wave's 16 q-rows

  const u16* qbase = QKV + (size_t)(b * S_ + q0 + fr) * QS + (size_t)h * HD;
  bf16x8 qf[4];
#pragma unroll
  for (int kk = 0; kk < 4; ++kk) qf[kk] = as_bf16x8(*(const u16x8*)(qbase + kk * 32 + kq * 8));

  f32x4 o[8] = {};
  float mrow = -1e30f;                         // softmax state for q = q0+fr
  float lrow = 0.f;

  const u16* kbase = QKV + (size_t)(b * S_) * QS + KOFF + (size_t)kvh * HD;
  const u16* vbase = Vt + (size_t)(b * NKV + kvh) * ((size_t)HD * S_);
  // exp2 constant: scale * log2(e) = (1/sqrt(128)) * 1.4426950408889634
  const float SC2 = 0.12751745f;
  const float THR = 90.5f;                     // 8 / scale (raw-domain defer-max)

  // staging geometry (512 threads): K 64x256B in 16B chunks (2/thread),
  // V 128x128B in 16B chunks (2/thread), written straight to padded rows.
  int krow0 = t >> 4, kc = t & 15;             // K: idx = ps*512 + t
  int vrow0 = t >> 3, vc = t & 7;              // V: idx = ps*512 + t

  int niter = (qt * 32 + 31) / 64 + 1;
  int qr = q0 + fr;                            // this lane's q-row

  // ---- prologue: load tile 0 into regs
  u16x8 kreg[2], vreg[2];
#pragma unroll
  for (int ps = 0; ps < 2; ++ps) {
    int row = krow0 + ps * 32;
    kreg[ps] = *(const u16x8*)(kbase + (size_t)row * QS + kc * 8);
    int vrow = vrow0 + ps * 64;
    vreg[ps] = *(const u16x8*)(vbase + (size_t)vrow * S_ + vc * 8);
  }

  for (int kt = 0; kt < niter; ++kt) {
    int k0 = kt * 64;
    if (kt) __syncthreads();   // all waves done reading LDS tile kt-1
    // ---- write staged regs -> LDS (K: 16B chunks, chunk' = c ^ (row&15))
#pragma unroll
    for (int ps = 0; ps < 2; ++ps) {
      int row = krow0 + ps * 32;
      *(u16x8*)&Ks[row * 128 + ((kc ^ row) & 15) * 8] = kreg[ps];
      int vrow = vrow0 + ps * 64;
      *(u16x8*)&Vs[vrow][vc * 8] = vreg[ps];
    }
    __syncthreads();           // tile kt visible to all waves
    // ---- T14: issue loads for tile kt+1 (consumed next iteration)
    if (kt + 1 < niter) {
      int k1 = k0 + 64;
#pragma unroll
      for (int ps = 0; ps < 2; ++ps) {
        int row = krow0 + ps * 32;
        kreg[ps] = *(const u16x8*)(kbase + (size_t)(k1 + row) * QS + kc * 8);
        int vrow = vrow0 + ps * 64;
        vreg[ps] = *(const u16x8*)(vbase + (size_t)vrow * S_ + k1 + vc * 8);
      }
    }

    // ---- S^T = K Q^T (swapped operands; identical frag registers)
    // s[j][r] = S_raw[q = q0+fr][k = k0 + j*16 + kq*4 + r]
    f32x4 s[4] = {};
    __builtin_amdgcn_s_setprio(1);
#pragma unroll
    for (int kk = 0; kk < 4; ++kk) {
#pragma unroll
      for (int j = 0; j < 4; ++j) {
        bf16x8 kf = as_bf16x8(*(const u16x8*)&Ks[(j * 16 + fr) * 128 + (((kk * 4 + kq) ^ fr) & 15) * 8]);
        s[j] = __builtin_amdgcn_mfma_f32_16x16x32_bf16(kf, qf[kk], s[j], 0, 0, 0);
      }
    }
    __builtin_amdgcn_s_setprio(0);

    // ---- causal mask only on diagonal tiles; in-lane row max
    float m_l = -1e30f;
    if (k0 + 63 > q0) {
#pragma unroll
      for (int j = 0; j < 4; ++j) {
        int kvb = k0 + j * 16 + kq * 4;
#pragma unroll
        for (int r = 0; r < 4; ++r) {
          float sv = (kvb + r <= qr) ? s[j][r] : -1e30f;
          s[j][r] = sv;
          m_l = fmaxf(m_l, sv);
        }
      }
    } else {
#pragma unroll
      for (int j = 0; j < 4; ++j)
#pragma unroll
        for (int r = 0; r < 4; ++r) m_l = fmaxf(m_l, s[j][r]);
    }
    // cross-kq reduce (lanes fr, fr+16, fr+32, fr+48): 2 stages only
    m_l = fmaxf(m_l, __shfl_xor(m_l, 16, 64));
    m_l = fmaxf(m_l, __shfl_xor(m_l, 32, 64));

    // ---- T13 defer-max (scalar state); o rows live at q=kq*4+r -> fetch
    // alphas from the matching fr-lanes (kq-group-uniform values).
    if (!__all(m_l - mrow <= THR)) {
      float mn = fmaxf(mrow, m_l);
      float a = fast_exp2((mrow - mn) * SC2);
      mrow = mn;
      lrow *= a;
#pragma unroll
      for (int r = 0; r < 4; ++r) {
        float ar = __shfl(a, kq * 4 + r, 64);
#pragma unroll
        for (int tt = 0; tt < 8; ++tt) o[tt][r] *= ar;
      }
    }

    // ---- P = exp2((s - m) * SC2); in-lane sum + 2-stage cross-kq
    float lt = 0.f;
#pragma unroll
    for (int j = 0; j < 4; ++j)
#pragma unroll
      for (int r = 0; r < 4; ++r) {
        float p = fast_exp2((s[j][r] - mrow) * SC2);
        s[j][r] = p;
        lt += p;
      }
    lt += __shfl_xor(lt, 16, 64);
    lt += __shfl_xor(lt, 32, 64);
    lrow += lt;

    // ---- P rows are lane-local: pack 4 consecutive k as one b64 store
#pragma unroll
    for (int j = 0; j < 4; ++j) {
      u16x4 pk;
#pragma unroll
      for (int r = 0; r < 4; ++r) pk[r] = f2bf(s[j][r]);
      *(u16x4*)&Plds[w][fr][j * 16 + kq * 4] = pk;
    }

    // ---- PV (unchanged; Plds read layout identical to previous rounds)
#pragma unroll
    for (int st = 0; st < 2; ++st) {
      bf16x8 pf = as_bf16x8(*(const u16x8*)&Plds[w][fr][st * 32 + kq * 8]);
      __builtin_amdgcn_s_setprio(1);
#pragma unroll
      for (int tt = 0; tt < 8; ++tt) {
        bf16x8 vv = as_bf16x8(*(const u16x8*)&Vs[tt * 16 + fr][st * 32 + kq * 8]);
        o[tt] = __builtin_amdgcn_mfma_f32_16x16x32_bf16(pf, vv, o[tt], 0, 0, 0);
      }
      __builtin_amdgcn_s_setprio(0);
    }
  }

  // inv for o's q-rows (kq*4+r) from the matching fr-lanes' lrow
  float inv[4];
#pragma unroll
  for (int r = 0; r < 4; ++r) inv[r] = 1.0f / __shfl(lrow, kq * 4 + r, 64);
  u16* obase = O + (size_t)(b * S_ + q0) * H_ + (size_t)h * HD;
#pragma unroll
  for (int tt = 0; tt < 8; ++tt)
#pragma unroll
    for (int r = 0; r < 4; ++r)
      obase[(size_t)(kq * 4 + r) * H_ + tt * 16 + fr] = f2bf(o[tt][r] * inv[r]);
}

// ---------------------------------------------------------------------------
extern "C" void kernel_launch(void* const* d_in, const int* in_sizes, int n_in,
                              void* d_out, int out_size, void* d_ws, size_t ws_size,
                              hipStream_t stream) {
  const float* X  = (const float*)d_in[0];
  const float* Wq = (const float*)d_in[2];
  const float* Wk = (const float*)d_in[3];
  const float* Wv = (const float*)d_in[4];
  const float* Wo = (const float*)d_in[5];
  float* out = (float*)d_out;

  // ws (80 MiB): Wtk 8 | Vt 8 | {Xb -> Ob} 32 | Wtq 32   (bf16)
  char* ws = (char*)d_ws;
  u16* Wtk = (u16*)ws;
  u16* Vt  = (u16*)(ws + 8ull  * 1024 * 1024);
  u16* Xb  = (u16*)(ws + 16ull * 1024 * 1024);
  u16* Ob  = (u16*)(ws + 16ull * 1024 * 1024);
  u16* Wtq = (u16*)(ws + 48ull * 1024 * 1024);
  // d_out (64 MiB fp32): QKV bf16 [4096][6144] = 48 MiB | Wtv 8 MiB | spare.
  u16* QKV = (u16*)d_out;
  u16* Wtv = (u16*)((char*)d_out + 48ull * 1024 * 1024);

  dim3 blk(256);
  dim3 blk8(512);

  // X -> bf16 (once; enables global_load_lds staging in all GEMMs)
  conv_bf16<<<dim3((size_t)BS * H_ / 8 / 256), blk, 0, stream>>>(X, Xb);

  // weight transposes (one dispatch for Wq/Wk/Wv)
  conv_transpose_w3<<<dim3(64, 64, 3), blk, 0, stream>>>(Wq, Wk, Wv, Wtq, Wtk, Wtv);

  // QKV = Xb @ [Wq | Wk | Wv]  (one dispatch, 1536 blocks = 6/CU)
  gemm_qkv<<<dim3(32, 48), blk, 0, stream>>>(Xb, Wtq, Wtk, Wtv, QKV);

  // RoPE in-place on Q and K (unified QKV addressing)
  rope_kernel<<<dim3((BS * 40 * 64) / 256), blk, 0, stream>>>(QKV);
  // V -> Vt
  transpose_v<<<dim3(S_ / 64, HD / 64, B_ * NKV), blk, 0, stream>>>(QKV, Vt);
  // attention -> Ob
  flash_attn<<<dim3(S_ / 32, NKV, B_), blk8, 0, stream>>>(QKV, Vt, Ob);
  // out = Ob @ Wo  (fp32 out, overwrites all of d_out)
  conv_transpose_w<<<dim3(64, 64), blk, 0, stream>>>(Wo, Wtq, H_, H_);
  gemm_bt_lds<true><<<dim3(32, 32), blk, 0, stream>>>(Ob, Wtq, out, BS, H_, H_);
}